// Round 2
// baseline (1185.941 us; speedup 1.0000x reference)
//
#include <hip/hip_runtime.h>
#include <hip/hip_bf16.h>
#include <float.h>
#include <math.h>

typedef __hip_bfloat16 bf16;

#define SEQ    512   // n
#define CDIM   256   // DIM
#define NH     8     // heads
#define DH     64    // dim_head
#define INNERD 512   // h*d
#define RT     32    // tie_attn_dim r
#define NB     2     // b
#define KW     15
#define PW     7

__device__ __forceinline__ float b2f(bf16 v) { return __bfloat162float(v); }
__device__ __forceinline__ bf16  f2b(float v) { return __float2bfloat16(v); }

// ---------------- rotary sin/cos table: tab[(i*32+j)*2] = sin, +1 = cos ----
__global__ void sincos_kernel(float* __restrict__ tab) {
    int idx = blockIdx.x * blockDim.x + threadIdx.x;   // 512*32
    if (idx >= SEQ * 32) return;
    int i = idx >> 5, j = idx & 31;
    float inv_freq = powf(10000.0f, -(float)j / 32.0f);
    float th = (float)i * inv_freq;
    float s, c;
    sincosf(th, &s, &c);
    tab[idx * 2]     = s;
    tab[idx * 2 + 1] = c;
}

// ---------------- mask stats: m_any[b][i], has_rows[b][r], inv_nr[b] -------
__global__ void mask_stats_kernel(const int* __restrict__ mask,
                                  int* __restrict__ m_any,
                                  int* __restrict__ has_rows,
                                  float* __restrict__ inv_nr) {
    int b = blockIdx.x;        // 2 blocks, 512 threads
    int i = threadIdx.x;
    int any_col = 0;
    for (int rr = 0; rr < RT; ++rr)
        any_col |= mask[(size_t)(b * RT + rr) * SEQ + i];
    m_any[b * SEQ + i] = any_col ? 1 : 0;

    __shared__ int hr[RT];
    if (i < RT) {
        int a = 0;
        const int* mrow = mask + (size_t)(b * RT + i) * SEQ;
        for (int j = 0; j < SEQ; ++j) a |= mrow[j];
        hr[i] = a ? 1 : 0;
        has_rows[b * RT + i] = hr[i];
    }
    __syncthreads();
    if (i == 0) {
        int s = 0;
        for (int rr = 0; rr < RT; ++rr) s += hr[rr];
        inv_nr[b] = (s > 0) ? rsqrtf((float)s) : 0.0f;
    }
}

// ---------------- depthwise conv1d (k=15, pad=7) → hdw[bn, i, c] f32 -------
__global__ void conv_kernel(const float* __restrict__ x,
                            const float* __restrict__ dw_w,
                            const float* __restrict__ dw_b,
                            float* __restrict__ hdw) {
    int m = blockIdx.x;            // bn*512 + i, 32768 blocks
    int c = threadIdx.x;           // 256 threads
    int bn = m >> 9, i = m & (SEQ - 1);
    const float* xb = x + (size_t)bn * SEQ * CDIM;
    float acc = dw_b[c];
    #pragma unroll
    for (int k = 0; k < KW; ++k) {
        int pos = i + k - PW;
        if (pos >= 0 && pos < SEQ)
            acc += xb[(size_t)pos * CDIM + c] * dw_w[c * KW + k];
    }
    hdw[(size_t)m * CDIM + c] = acc;
}

// ---------------- q GEMM: q = hdw[32768,256] @ pw_w^T[256,512] + pw_b ------
// epilogue: rotary + has_rows zeroing + scale(0.125*inv_nr) → Qr bf16
// Qr layout: [((b*8+h)*512 + i)*2048 + rr*64 + dd]
__global__ void qgemm_kernel(const float* __restrict__ A,    // hdw
                             const float* __restrict__ Bw,   // pw_w [512,256]
                             const float* __restrict__ bias, // pw_b
                             const int* __restrict__ has_rows,
                             const float* __restrict__ inv_nr,
                             const float* __restrict__ tab,
                             bf16* __restrict__ Qr) {
    __shared__ float As[16][68];
    __shared__ float Bs[16][68];
    int m0 = blockIdx.y * 64;
    int n0 = blockIdx.x * 64;
    int tid = threadIdx.x;
    int tn = tid & 15, tm = tid >> 4;
    float acc[4][4] = {};
    for (int k0 = 0; k0 < CDIM; k0 += 16) {
        #pragma unroll
        for (int l = 0; l < 4; ++l) {
            int lin = l * 256 + tid;
            int mm = lin >> 4, kk = lin & 15;
            As[kk][mm] = A[(size_t)(m0 + mm) * CDIM + k0 + kk];
        }
        #pragma unroll
        for (int l = 0; l < 4; ++l) {
            int lin = l * 256 + tid;
            int nn = lin >> 4, kk = lin & 15;
            Bs[kk][nn] = Bw[(size_t)(n0 + nn) * CDIM + k0 + kk];
        }
        __syncthreads();
        #pragma unroll
        for (int kk = 0; kk < 16; ++kk) {
            float a[4], bv[4];
            #pragma unroll
            for (int t = 0; t < 4; ++t) a[t] = As[kk][tm * 4 + t];
            #pragma unroll
            for (int t = 0; t < 4; ++t) bv[t] = Bs[kk][tn * 4 + t];
            #pragma unroll
            for (int im = 0; im < 4; ++im)
                #pragma unroll
                for (int in_ = 0; in_ < 4; ++in_)
                    acc[im][in_] += a[im] * bv[in_];
        }
        __syncthreads();
    }
    #pragma unroll
    for (int im = 0; im < 4; ++im) {
        int m = m0 + tm * 4 + im;
        int i = m & (SEQ - 1);
        int bn = m >> 9;
        int b = bn >> 5, rr = bn & 31;
        float zscale = has_rows[bn] ? 0.125f * inv_nr[b] : 0.0f;
        #pragma unroll
        for (int in_ = 0; in_ < 4; in_ += 2) {
            int o = n0 + tn * 4 + in_;
            float q0 = acc[im][in_]     + bias[o];
            float q1 = acc[im][in_ + 1] + bias[o + 1];
            int h = o >> 6, dd = o & 63;
            int j = dd >> 1;
            float sn = tab[(i * 32 + j) * 2], cs = tab[(i * 32 + j) * 2 + 1];
            float r0 = (q0 * cs - q1 * sn) * zscale;
            float r1 = (q1 * cs + q0 * sn) * zscale;
            size_t base = ((size_t)((b * NH + h) * SEQ + i)) * 2048 + rr * 64 + dd;
            Qr[base]     = f2b(r0);
            Qr[base + 1] = f2b(r1);
        }
    }
}

// ---------------- kv GEMM: kv = x[32768,256] @ w_kv[256,1024] --------------
// epilogue: o<512 → rotary → Kr ; o>=512 → Vr (same layout as Qr)
__global__ void kvgemm_kernel(const float* __restrict__ A,   // x
                              const float* __restrict__ Bw,  // w_kv [256,1024]
                              const float* __restrict__ tab,
                              bf16* __restrict__ Kr,
                              bf16* __restrict__ Vr) {
    __shared__ float As[16][68];
    __shared__ float Bs[16][68];
    int m0 = blockIdx.y * 64;
    int n0 = blockIdx.x * 64;   // 0..960
    int tid = threadIdx.x;
    int tn = tid & 15, tm = tid >> 4;
    float acc[4][4] = {};
    for (int k0 = 0; k0 < CDIM; k0 += 16) {
        #pragma unroll
        for (int l = 0; l < 4; ++l) {
            int lin = l * 256 + tid;
            int mm = lin >> 4, kk = lin & 15;
            As[kk][mm] = A[(size_t)(m0 + mm) * CDIM + k0 + kk];
        }
        #pragma unroll
        for (int l = 0; l < 4; ++l) {
            int lin = l * 256 + tid;
            int kk = lin >> 6, nn = lin & 63;
            Bs[kk][nn] = Bw[(size_t)(k0 + kk) * 1024 + n0 + nn];
        }
        __syncthreads();
        #pragma unroll
        for (int kk = 0; kk < 16; ++kk) {
            float a[4], bv[4];
            #pragma unroll
            for (int t = 0; t < 4; ++t) a[t] = As[kk][tm * 4 + t];
            #pragma unroll
            for (int t = 0; t < 4; ++t) bv[t] = Bs[kk][tn * 4 + t];
            #pragma unroll
            for (int im = 0; im < 4; ++im)
                #pragma unroll
                for (int in_ = 0; in_ < 4; ++in_)
                    acc[im][in_] += a[im] * bv[in_];
        }
        __syncthreads();
    }
    #pragma unroll
    for (int im = 0; im < 4; ++im) {
        int m = m0 + tm * 4 + im;
        int i = m & (SEQ - 1);
        int bn = m >> 9;
        int b = bn >> 5, rr = bn & 31;
        #pragma unroll
        for (int in_ = 0; in_ < 4; in_ += 2) {
            int o = n0 + tn * 4 + in_;
            float v0 = acc[im][in_], v1 = acc[im][in_ + 1];
            if (o < INNERD) {
                int h = o >> 6, dd = o & 63;
                int j = dd >> 1;
                float sn = tab[(i * 32 + j) * 2], cs = tab[(i * 32 + j) * 2 + 1];
                float r0 = v0 * cs - v1 * sn;
                float r1 = v1 * cs + v0 * sn;
                size_t base = ((size_t)((b * NH + h) * SEQ + i)) * 2048 + rr * 64 + dd;
                Kr[base]     = f2b(r0);
                Kr[base + 1] = f2b(r1);
            } else {
                int oo = o - INNERD;
                int h = oo >> 6, dd = oo & 63;
                size_t base = ((size_t)((b * NH + h) * SEQ + i)) * 2048 + rr * 64 + dd;
                Vr[base]     = f2b(v0);
                Vr[base + 1] = f2b(v1);
            }
        }
    }
}

// ---------------- dots: per (b,h): S[i,j] = sum_k Qr[i,k]*Kr[j,k], K=2048 --
__global__ void dots_kernel(const bf16* __restrict__ Qr,
                            const bf16* __restrict__ Kr,
                            float* __restrict__ Sbuf) {
    int bh = blockIdx.z;
    const bf16* A = Qr + (size_t)bh * SEQ * 2048;
    const bf16* B = Kr + (size_t)bh * SEQ * 2048;
    float* S = Sbuf + (size_t)bh * SEQ * SEQ;
    __shared__ float As[16][68];
    __shared__ float Bs[16][68];
    int m0 = blockIdx.y * 64;
    int n0 = blockIdx.x * 64;
    int tid = threadIdx.x;
    int tn = tid & 15, tm = tid >> 4;
    float acc[4][4] = {};
    for (int k0 = 0; k0 < 2048; k0 += 16) {
        #pragma unroll
        for (int l = 0; l < 4; ++l) {
            int lin = l * 256 + tid;
            int mm = lin >> 4, kk = lin & 15;
            As[kk][mm] = b2f(A[(size_t)(m0 + mm) * 2048 + k0 + kk]);
        }
        #pragma unroll
        for (int l = 0; l < 4; ++l) {
            int lin = l * 256 + tid;
            int nn = lin >> 4, kk = lin & 15;
            Bs[kk][nn] = b2f(B[(size_t)(n0 + nn) * 2048 + k0 + kk]);
        }
        __syncthreads();
        #pragma unroll
        for (int kk = 0; kk < 16; ++kk) {
            float a[4], bv[4];
            #pragma unroll
            for (int t = 0; t < 4; ++t) a[t] = As[kk][tm * 4 + t];
            #pragma unroll
            for (int t = 0; t < 4; ++t) bv[t] = Bs[kk][tn * 4 + t];
            #pragma unroll
            for (int im = 0; im < 4; ++im)
                #pragma unroll
                for (int in_ = 0; in_ < 4; ++in_)
                    acc[im][in_] += a[im] * bv[in_];
        }
        __syncthreads();
    }
    #pragma unroll
    for (int im = 0; im < 4; ++im)
        #pragma unroll
        for (int in_ = 0; in_ < 4; ++in_)
            S[(size_t)(m0 + tm * 4 + im) * SEQ + n0 + tn * 4 + in_] = acc[im][in_];
}

// ---------------- softmax over j with pair mask ----------------------------
__global__ void softmax_kernel(const int* __restrict__ m_any,
                               float* __restrict__ Sbuf) {
    int i = blockIdx.x, bh = blockIdx.y;
    int b = bh >> 3;
    float* row = Sbuf + ((size_t)bh * SEQ + i) * SEQ;
    const int* ma = m_any + b * SEQ;
    int fi = ma[i];
    int t = threadIdx.x;   // 256 threads, 2 elems each
    float v0 = (fi && ma[t])       ? row[t]       : -FLT_MAX;
    float v1 = (fi && ma[t + 256]) ? row[t + 256] : -FLT_MAX;
    __shared__ float red[256];
    red[t] = fmaxf(v0, v1);
    __syncthreads();
    for (int s = 128; s > 0; s >>= 1) {
        if (t < s) red[t] = fmaxf(red[t], red[t + s]);
        __syncthreads();
    }
    float mx = red[0];
    __syncthreads();
    float e0 = __expf(v0 - mx);
    float e1 = __expf(v1 - mx);
    red[t] = e0 + e1;
    __syncthreads();
    for (int s = 128; s > 0; s >>= 1) {
        if (t < s) red[t] += red[t + s];
        __syncthreads();
    }
    float inv = 1.0f / red[0];
    row[t]       = e0 * inv;
    row[t + 256] = e1 * inv;
}

// ---------------- PV: per (b,h): O[i, rd] = sum_j P[i,j] * Vr[j, rd] -------
// epilogue scatter: Obuf[((b*32+rr)*512 + i)*512 + h*64 + dd] bf16
__global__ void pv_kernel(const float* __restrict__ Sbuf,
                          const bf16* __restrict__ Vr,
                          bf16* __restrict__ Obuf) {
    int bh = blockIdx.z;
    int b = bh >> 3, h = bh & 7;
    const float* A = Sbuf + (size_t)bh * SEQ * SEQ;
    const bf16* B = Vr + (size_t)bh * SEQ * 2048;
    __shared__ float As[16][68];
    __shared__ float Bs[16][68];
    int m0 = blockIdx.y * 64;
    int n0 = blockIdx.x * 64;   // rd
    int tid = threadIdx.x;
    int tn = tid & 15, tm = tid >> 4;
    float acc[4][4] = {};
    for (int k0 = 0; k0 < SEQ; k0 += 16) {
        #pragma unroll
        for (int l = 0; l < 4; ++l) {
            int lin = l * 256 + tid;
            int mm = lin >> 4, kk = lin & 15;
            As[kk][mm] = A[(size_t)(m0 + mm) * SEQ + k0 + kk];
        }
        #pragma unroll
        for (int l = 0; l < 4; ++l) {
            int lin = l * 256 + tid;
            int kk = lin >> 6, nn = lin & 63;
            Bs[kk][nn] = b2f(B[(size_t)(k0 + kk) * 2048 + n0 + nn]);
        }
        __syncthreads();
        #pragma unroll
        for (int kk = 0; kk < 16; ++kk) {
            float a[4], bv[4];
            #pragma unroll
            for (int t = 0; t < 4; ++t) a[t] = As[kk][tm * 4 + t];
            #pragma unroll
            for (int t = 0; t < 4; ++t) bv[t] = Bs[kk][tn * 4 + t];
            #pragma unroll
            for (int im = 0; im < 4; ++im)
                #pragma unroll
                for (int in_ = 0; in_ < 4; ++in_)
                    acc[im][in_] += a[im] * bv[in_];
        }
        __syncthreads();
    }
    #pragma unroll
    for (int im = 0; im < 4; ++im) {
        int i = m0 + tm * 4 + im;
        #pragma unroll
        for (int in_ = 0; in_ < 4; ++in_) {
            int nidx = n0 + tn * 4 + in_;
            int rr = nidx >> 6, dd = nidx & 63;
            Obuf[((size_t)((b * RT + rr) * SEQ + i)) * INNERD + h * DH + dd] =
                f2b(acc[im][in_]);
        }
    }
}

// ---------------- final: out = Obuf[32768,512] @ w_o[512,256] + b_o --------
__global__ void out_kernel(const bf16* __restrict__ A,    // Obuf (internal bf16)
                           const float* __restrict__ Bw,  // w_o [512,256]
                           const float* __restrict__ bias,
                           float* __restrict__ out) {
    __shared__ float As[16][68];
    __shared__ float Bs[16][68];
    int m0 = blockIdx.y * 64;
    int n0 = blockIdx.x * 64;
    int tid = threadIdx.x;
    int tn = tid & 15, tm = tid >> 4;
    float acc[4][4] = {};
    for (int k0 = 0; k0 < INNERD; k0 += 16) {
        #pragma unroll
        for (int l = 0; l < 4; ++l) {
            int lin = l * 256 + tid;
            int mm = lin >> 4, kk = lin & 15;
            As[kk][mm] = b2f(A[(size_t)(m0 + mm) * INNERD + k0 + kk]);
        }
        #pragma unroll
        for (int l = 0; l < 4; ++l) {
            int lin = l * 256 + tid;
            int kk = lin >> 6, nn = lin & 63;
            Bs[kk][nn] = Bw[(size_t)(k0 + kk) * CDIM + n0 + nn];
        }
        __syncthreads();
        #pragma unroll
        for (int kk = 0; kk < 16; ++kk) {
            float a[4], bv[4];
            #pragma unroll
            for (int t = 0; t < 4; ++t) a[t] = As[kk][tm * 4 + t];
            #pragma unroll
            for (int t = 0; t < 4; ++t) bv[t] = Bs[kk][tn * 4 + t];
            #pragma unroll
            for (int im = 0; im < 4; ++im)
                #pragma unroll
                for (int in_ = 0; in_ < 4; ++in_)
                    acc[im][in_] += a[im] * bv[in_];
        }
        __syncthreads();
    }
    #pragma unroll
    for (int im = 0; im < 4; ++im) {
        int m = m0 + tm * 4 + im;
        #pragma unroll
        for (int in_ = 0; in_ < 4; ++in_) {
            int c = n0 + tn * 4 + in_;
            out[(size_t)m * CDIM + c] = acc[im][in_] + bias[c];
        }
    }
}

// ---------------- workspace layout (bytes) ---------------------------------
// 0        : sincos tab f32 [512*32*2]          131072
// 131072   : m_any   int32 [1024]                 4096
// 135168   : has_rows int32 [64]                   256
// 135424   : inv_nr  f32 [2] (+pad)                256
// 135680   : hdw f32 [8388608]  (REUSED for Obuf bf16 [16777216] after qgemm)
// 33690112 : Sbuf f32 [16*512*512]            16777216
// 50467328 : Qr bf16 [16777216]               33554432
// 84021760 : Kr bf16 [16777216]               33554432
// 117576192: Vr bf16 [16777216]               33554432
// end      : 151130624 (~144.1 MB)

extern "C" void kernel_launch(void* const* d_in, const int* in_sizes, int n_in,
                              void* d_out, int out_size, void* d_ws, size_t ws_size,
                              hipStream_t stream) {
    const float* x    = (const float*)d_in[0];
    const int*   mask = (const int*)d_in[1];
    const float* dw_w = (const float*)d_in[3];
    const float* dw_b = (const float*)d_in[4];
    const float* pw_w = (const float*)d_in[5];
    const float* pw_b = (const float*)d_in[6];
    const float* w_kv = (const float*)d_in[7];
    const float* w_o  = (const float*)d_in[8];
    const float* b_o  = (const float*)d_in[9];
    float* out = (float*)d_out;

    char* ws = (char*)d_ws;
    float* tab   = (float*)(ws + 0);
    int*   m_any = (int*)(ws + 131072);
    int*   hrows = (int*)(ws + 135168);
    float* invnr = (float*)(ws + 135424);
    float* hdw   = (float*)(ws + 135680);
    float* Sbuf  = (float*)(ws + 33690112);
    bf16*  Qr    = (bf16*)(ws + 50467328);
    bf16*  Kr    = (bf16*)(ws + 84021760);
    bf16*  Vr    = (bf16*)(ws + 117576192);
    bf16*  Obuf  = (bf16*)(ws + 135680);   // reuse hdw region (hdw dead after qgemm)

    if (ws_size < 151130624u) return;  // insufficient scratch → fail loudly

    hipLaunchKernelGGL(sincos_kernel,   dim3(64),          dim3(256), 0, stream, tab);
    hipLaunchKernelGGL(mask_stats_kernel, dim3(NB),        dim3(512), 0, stream, mask, m_any, hrows, invnr);
    hipLaunchKernelGGL(conv_kernel,     dim3(64 * SEQ),    dim3(256), 0, stream, x, dw_w, dw_b, hdw);
    hipLaunchKernelGGL(qgemm_kernel,    dim3(8, 512),      dim3(256), 0, stream, hdw, pw_w, pw_b, hrows, invnr, tab, Qr);
    hipLaunchKernelGGL(kvgemm_kernel,   dim3(16, 512),     dim3(256), 0, stream, x, w_kv, tab, Kr, Vr);
    hipLaunchKernelGGL(dots_kernel,     dim3(8, 8, 16),    dim3(256), 0, stream, Qr, Kr, Sbuf);
    hipLaunchKernelGGL(softmax_kernel,  dim3(SEQ, 16),     dim3(256), 0, stream, m_any, Sbuf);
    hipLaunchKernelGGL(pv_kernel,       dim3(32, 8, 16),   dim3(256), 0, stream, Sbuf, Vr, Obuf);
    hipLaunchKernelGGL(out_kernel,      dim3(4, 512),      dim3(256), 0, stream, Obuf, w_o, b_o, out);
}

// Round 3
// 386.103 us; speedup vs baseline: 3.0716x; 3.0716x over previous
//
#include <hip/hip_runtime.h>
#include <hip/hip_bf16.h>
#include <float.h>
#include <math.h>

typedef __bf16 bfx;
typedef __attribute__((ext_vector_type(8))) __bf16 bf16x8;
typedef __attribute__((ext_vector_type(4))) float f32x4;

#define SEQ    512
#define CDIM   256
#define NH     8
#define DH     64
#define INNERD 512
#define RT     32
#define NB     2
#define KW     15
#define PW     7
#define LDT    40   // padded LDS row stride (bf16 elems): 80B -> 2-way conflicts max

// ---------------- rotary sin/cos table ------------------------------------
__global__ void sincos_kernel(float* __restrict__ tab) {
    int idx = blockIdx.x * blockDim.x + threadIdx.x;
    if (idx >= SEQ * 32) return;
    int i = idx >> 5, j = idx & 31;
    float inv_freq = powf(10000.0f, -(float)j / 32.0f);
    float s, c;
    sincosf((float)i * inv_freq, &s, &c);
    tab[idx * 2] = s;
    tab[idx * 2 + 1] = c;
}

// ---------------- mask stats ----------------------------------------------
__global__ void mask_stats_kernel(const int* __restrict__ mask,
                                  int* __restrict__ m_any,
                                  int* __restrict__ has_rows,
                                  float* __restrict__ inv_nr) {
    int b = blockIdx.x;
    int i = threadIdx.x;
    int any_col = 0;
    for (int rr = 0; rr < RT; ++rr)
        any_col |= mask[(size_t)(b * RT + rr) * SEQ + i];
    m_any[b * SEQ + i] = any_col ? 1 : 0;
    __shared__ int hr[RT];
    if (i < RT) {
        int a = 0;
        const int* mrow = mask + (size_t)(b * RT + i) * SEQ;
        for (int j = 0; j < SEQ; ++j) a |= mrow[j];
        hr[i] = a ? 1 : 0;
        has_rows[b * RT + i] = hr[i];
    }
    __syncthreads();
    if (i == 0) {
        int s = 0;
        for (int rr = 0; rr < RT; ++rr) s += hr[rr];
        inv_nr[b] = (s > 0) ? rsqrtf((float)s) : 0.0f;
    }
}

// ---------------- f32 -> bf16 flat convert (4 elems/thread) ----------------
__global__ void cvt_kernel(const float* __restrict__ src, bfx* __restrict__ dst, int n4) {
    int idx = blockIdx.x * blockDim.x + threadIdx.x;
    if (idx >= n4) return;
    float4 v = ((const float4*)src)[idx];
    bfx* d = dst + idx * 4;
    d[0] = (bfx)v.x; d[1] = (bfx)v.y; d[2] = (bfx)v.z; d[3] = (bfx)v.w;
}

// ---------------- transpose + convert: dst[n*K+k] = src[k*N+n] -------------
__global__ void tcvt_kernel(const float* __restrict__ src, bfx* __restrict__ dst,
                            int Klog2, int N, int total) {
    int idx = blockIdx.x * blockDim.x + threadIdx.x;
    if (idx >= total) return;
    int k = idx & ((1 << Klog2) - 1), n = idx >> Klog2;
    dst[idx] = (bfx)src[(size_t)k * N + n];
}

// ---------------- depthwise conv1d, register sliding window → hdw bf16 ----
__global__ void conv_kernel(const bfx* __restrict__ xb,
                            const float* __restrict__ dw_w,
                            const float* __restrict__ dw_b,
                            bfx* __restrict__ hdw) {
    int bn = blockIdx.x;           // 64
    int i0 = blockIdx.y * 128;     // 4 chunks
    int c  = threadIdx.x;          // 256
    const bfx* xc = xb + (size_t)bn * SEQ * CDIM + c;
    float w[KW];
    #pragma unroll
    for (int k = 0; k < KW; ++k) w[k] = dw_w[c * KW + k];
    float bias = dw_b[c];
    float win[KW];
    #pragma unroll
    for (int k = 0; k < KW; ++k) {
        int p = i0 - PW + k;
        win[k] = (p >= 0 && p < SEQ) ? (float)xc[(size_t)p * CDIM] : 0.0f;
    }
    for (int i = i0; i < i0 + 128; ++i) {
        float acc = bias;
        #pragma unroll
        for (int k = 0; k < KW; ++k) acc += win[k] * w[k];
        hdw[((size_t)bn * SEQ + i) * CDIM + c] = (bfx)acc;
        #pragma unroll
        for (int k = 0; k < KW - 1; ++k) win[k] = win[k + 1];
        int p = i + PW + 1;
        win[KW - 1] = (p < SEQ) ? (float)xc[(size_t)p * CDIM] : 0.0f;
    }
}

// ---------------- shared 128x128 MFMA tile ---------------------------------
// A [m][k] row-major, B [n][k] row-major (i.e. B^T), K % 32 == 0.
// 256 threads = 4 waves in 2x2; each wave 64x64 = 4x4 frags of 16x16x32.
__device__ __forceinline__ void gemm_tile(const bfx* __restrict__ A, int lda,
                                          const bfx* __restrict__ B, int ldb,
                                          int m0, int n0, int K,
                                          bfx* As, bfx* Bs, f32x4 acc[4][4]) {
    int tid = threadIdx.x;
    int wave = tid >> 6, lane = tid & 63;
    int wm = (wave >> 1) * 64, wn = (wave & 1) * 64;
    int col = lane & 15, quad = lane >> 4;
    for (int k0 = 0; k0 < K; k0 += 32) {
        #pragma unroll
        for (int r = 0; r < 2; ++r) {
            int v = tid + r * 256;               // 512 vectors of 8 per matrix
            int row = v >> 2, kv = (v & 3) * 8;
            *(bf16x8*)&As[row * LDT + kv] = *(const bf16x8*)&A[(size_t)(m0 + row) * lda + k0 + kv];
            *(bf16x8*)&Bs[row * LDT + kv] = *(const bf16x8*)&B[(size_t)(n0 + row) * ldb + k0 + kv];
        }
        __syncthreads();
        bf16x8 af[4], bff[4];
        #pragma unroll
        for (int f = 0; f < 4; ++f) {
            af[f]  = *(const bf16x8*)&As[(wm + f * 16 + col) * LDT + quad * 8];
            bff[f] = *(const bf16x8*)&Bs[(wn + f * 16 + col) * LDT + quad * 8];
        }
        #pragma unroll
        for (int mi = 0; mi < 4; ++mi)
            #pragma unroll
            for (int ni = 0; ni < 4; ++ni)
                acc[mi][ni] = __builtin_amdgcn_mfma_f32_16x16x32_bf16(af[mi], bff[ni], acc[mi][ni], 0, 0, 0);
        __syncthreads();
    }
}

#define GEMM_PROLOGUE \
    __shared__ bfx As[128 * LDT]; \
    __shared__ bfx Bs[128 * LDT]; \
    f32x4 acc[4][4]; \
    _Pragma("unroll") for (int i_ = 0; i_ < 4; ++i_) \
    _Pragma("unroll") for (int j_ = 0; j_ < 4; ++j_) acc[i_][j_] = (f32x4){0.f, 0.f, 0.f, 0.f}; \
    int tid = threadIdx.x; \
    int wave = tid >> 6, lane = tid & 63; \
    int wm = (wave >> 1) * 64, wn = (wave & 1) * 64; \
    int col = lane & 15, quad = lane >> 4;

// ---------------- q GEMM: hdw[32768,256] @ pw16^T -> rotary -> Qr ----------
// Qr layout: [((b*8+h)*512 + i)*2048 + rr*64 + dd]
__global__ void qgemm_kernel(const bfx* __restrict__ A, const bfx* __restrict__ B,
                             const float* __restrict__ pw_b,
                             const int* __restrict__ has_rows,
                             const float* __restrict__ inv_nr,
                             const float* __restrict__ tab,
                             bfx* __restrict__ Qr) {
    GEMM_PROLOGUE
    int m0 = blockIdx.y * 128, n0 = blockIdx.x * 128;
    gemm_tile(A, CDIM, B, CDIM, m0, n0, CDIM, As, Bs, acc);
    int bn = m0 >> 9, b = bn >> 5, rr = bn & 31;
    float zs = has_rows[bn] ? 0.125f * inv_nr[b] : 0.0f;
    #pragma unroll
    for (int mi = 0; mi < 4; ++mi)
        #pragma unroll
        for (int ni = 0; ni < 4; ++ni)
            #pragma unroll
            for (int rg = 0; rg < 4; ++rg) {
                int m = m0 + wm + mi * 16 + quad * 4 + rg;
                int i = m & (SEQ - 1);
                int o = n0 + wn + ni * 16 + col;
                float v  = acc[mi][ni][rg];
                float vp = __shfl_xor(v, 1);
                float q  = v + pw_b[o];
                float qp = vp + pw_b[o ^ 1];
                int h = o >> 6, dd = o & 63, j = dd >> 1;
                float sn = tab[(i * 32 + j) * 2], cs = tab[(i * 32 + j) * 2 + 1];
                float r = (o & 1) ? (q * cs + qp * sn) : (q * cs - qp * sn);
                Qr[((size_t)((b * NH + h) * SEQ + i)) * 2048 + rr * 64 + dd] = (bfx)(r * zs);
            }
}

// ---------------- kv GEMM: xb[32768,256] @ wkvT^T -> Kr (rotary) / Vt ------
// Kr layout same as Qr; Vt layout: [((b*8+h)*2048 + rr*64+dd)*512 + i]
__global__ void kvgemm_kernel(const bfx* __restrict__ A, const bfx* __restrict__ B,
                              const float* __restrict__ tab,
                              bfx* __restrict__ Kr, bfx* __restrict__ Vt) {
    GEMM_PROLOGUE
    int m0 = blockIdx.y * 128, n0 = blockIdx.x * 128;
    gemm_tile(A, CDIM, B, CDIM, m0, n0, CDIM, As, Bs, acc);
    int bn = m0 >> 9, b = bn >> 5, rr = bn & 31;
    #pragma unroll
    for (int mi = 0; mi < 4; ++mi)
        #pragma unroll
        for (int ni = 0; ni < 4; ++ni)
            #pragma unroll
            for (int rg = 0; rg < 4; ++rg) {
                int m = m0 + wm + mi * 16 + quad * 4 + rg;
                int i = m & (SEQ - 1);
                int o = n0 + wn + ni * 16 + col;
                float v  = acc[mi][ni][rg];
                float vp = __shfl_xor(v, 1);
                if (o < INNERD) {
                    int h = o >> 6, dd = o & 63, j = dd >> 1;
                    float sn = tab[(i * 32 + j) * 2], cs = tab[(i * 32 + j) * 2 + 1];
                    float r = (o & 1) ? (v * cs + vp * sn) : (v * cs - vp * sn);
                    Kr[((size_t)((b * NH + h) * SEQ + i)) * 2048 + rr * 64 + dd] = (bfx)r;
                } else {
                    int oo = o - INNERD;
                    int h = oo >> 6, dd = oo & 63;
                    Vt[((size_t)((b * NH + h) * 2048 + rr * 64 + dd)) * SEQ + i] = (bfx)v;
                }
            }
}

// ---------------- dots: per bh: S = Qr[512,2048] @ Kr^T --------------------
__global__ void dots_kernel(const bfx* __restrict__ Qr, const bfx* __restrict__ Kr,
                            float* __restrict__ Sbuf) {
    GEMM_PROLOGUE
    int bh = blockIdx.z;
    int m0 = blockIdx.y * 128, n0 = blockIdx.x * 128;
    const bfx* A = Qr + (size_t)bh * SEQ * 2048;
    const bfx* B = Kr + (size_t)bh * SEQ * 2048;
    gemm_tile(A, 2048, B, 2048, m0, n0, 2048, As, Bs, acc);
    float* S = Sbuf + (size_t)bh * SEQ * SEQ;
    #pragma unroll
    for (int mi = 0; mi < 4; ++mi)
        #pragma unroll
        for (int ni = 0; ni < 4; ++ni)
            #pragma unroll
            for (int rg = 0; rg < 4; ++rg) {
                int i = m0 + wm + mi * 16 + quad * 4 + rg;
                int j = n0 + wn + ni * 16 + col;
                S[(size_t)i * SEQ + j] = acc[mi][ni][rg];
            }
}

// ---------------- softmax: Sbuf f32 -> Pb bf16 -----------------------------
__global__ void softmax_kernel(const int* __restrict__ m_any,
                               const float* __restrict__ Sbuf,
                               bfx* __restrict__ Pb) {
    int i = blockIdx.x, bh = blockIdx.y;
    int b = bh >> 3;
    const float* row = Sbuf + ((size_t)bh * SEQ + i) * SEQ;
    bfx* prow = Pb + ((size_t)bh * SEQ + i) * SEQ;
    const int* ma = m_any + b * SEQ;
    int fi = ma[i];
    int t = threadIdx.x;
    float v0 = (fi && ma[t])       ? row[t]       : -FLT_MAX;
    float v1 = (fi && ma[t + 256]) ? row[t + 256] : -FLT_MAX;
    __shared__ float red[256];
    red[t] = fmaxf(v0, v1);
    __syncthreads();
    for (int s = 128; s > 0; s >>= 1) {
        if (t < s) red[t] = fmaxf(red[t], red[t + s]);
        __syncthreads();
    }
    float mx = red[0];
    __syncthreads();
    float e0 = __expf(v0 - mx);
    float e1 = __expf(v1 - mx);
    red[t] = e0 + e1;
    __syncthreads();
    for (int s = 128; s > 0; s >>= 1) {
        if (t < s) red[t] += red[t + s];
        __syncthreads();
    }
    float inv = 1.0f / red[0];
    prow[t]       = (bfx)(e0 * inv);
    prow[t + 256] = (bfx)(e1 * inv);
}

// ---------------- PV: per bh: O[i,rd] = Pb[512,512] @ Vt[2048,512]^T -------
// scatter: Obuf[((b*32+rr)*512 + i)*512 + h*64 + dd]
__global__ void pv_kernel(const bfx* __restrict__ Pb, const bfx* __restrict__ Vt,
                          bfx* __restrict__ Obuf) {
    GEMM_PROLOGUE
    int bh = blockIdx.z;
    int b = bh >> 3, h = bh & 7;
    int m0 = blockIdx.y * 128, n0 = blockIdx.x * 128;
    const bfx* A = Pb + (size_t)bh * SEQ * SEQ;
    const bfx* B = Vt + (size_t)bh * 2048 * SEQ;
    gemm_tile(A, SEQ, B, SEQ, m0, n0, SEQ, As, Bs, acc);
    #pragma unroll
    for (int mi = 0; mi < 4; ++mi)
        #pragma unroll
        for (int ni = 0; ni < 4; ++ni)
            #pragma unroll
            for (int rg = 0; rg < 4; ++rg) {
                int i = m0 + wm + mi * 16 + quad * 4 + rg;
                int rd = n0 + wn + ni * 16 + col;
                int rr = rd >> 6, dd = rd & 63;
                Obuf[((size_t)((b * RT + rr) * SEQ + i)) * INNERD + h * DH + dd] =
                    (bfx)acc[mi][ni][rg];
            }
}

// ---------------- out: Obuf[32768,512] @ woT^T + b_o -> f32 ----------------
__global__ void out_kernel(const bfx* __restrict__ A, const bfx* __restrict__ B,
                           const float* __restrict__ b_o, float* __restrict__ out) {
    GEMM_PROLOGUE
    int m0 = blockIdx.y * 128, n0 = blockIdx.x * 128;
    gemm_tile(A, INNERD, B, INNERD, m0, n0, INNERD, As, Bs, acc);
    #pragma unroll
    for (int mi = 0; mi < 4; ++mi)
        #pragma unroll
        for (int ni = 0; ni < 4; ++ni)
            #pragma unroll
            for (int rg = 0; rg < 4; ++rg) {
                int m = m0 + wm + mi * 16 + quad * 4 + rg;
                int c = n0 + wn + ni * 16 + col;
                out[(size_t)m * CDIM + c] = acc[mi][ni][rg] + b_o[c];
            }
}

// ---------------- workspace layout (bytes) ---------------------------------
// 0         tab f32 [512*32*2]                      131072
// 131072    m_any int32[1024]                         4096
// 135168    has_rows int32[64]                         256
// 135424    inv_nr f32 (+pad)                          256
// 135680    xb16 bf16 [8388608]   16777216   (REUSED: Sbuf f32 [4194304] after kvgemm)
// 16912896  hdw  bf16 [8388608]   16777216   (REUSED: Pb bf16 [4194304] after qgemm)
// 33690112  pw16 bf16 [131072]      262144
// 33952256  wkvT bf16 [262144]      524288
// 34476544  woT  bf16 [131072]      262144
// 34738688  Qr   bf16 [16777216]  33554432   (REUSED: Obuf bf16 after dots)
// 68293120  Kr   bf16 [16777216]  33554432
// 101847552 Vt   bf16 [16777216]  33554432
// end 135401984 (~129.1 MB; Round-2 proved >=151 MB available)

extern "C" void kernel_launch(void* const* d_in, const int* in_sizes, int n_in,
                              void* d_out, int out_size, void* d_ws, size_t ws_size,
                              hipStream_t stream) {
    const float* x    = (const float*)d_in[0];
    const int*   mask = (const int*)d_in[1];
    const float* dw_w = (const float*)d_in[3];
    const float* dw_b = (const float*)d_in[4];
    const float* pw_w = (const float*)d_in[5];
    const float* pw_b = (const float*)d_in[6];
    const float* w_kv = (const float*)d_in[7];
    const float* w_o  = (const float*)d_in[8];
    const float* b_o  = (const float*)d_in[9];
    float* out = (float*)d_out;

    char* ws = (char*)d_ws;
    float* tab   = (float*)(ws + 0);
    int*   m_any = (int*)(ws + 131072);
    int*   hrows = (int*)(ws + 135168);
    float* invnr = (float*)(ws + 135424);
    bfx*   xb16  = (bfx*)(ws + 135680);
    float* Sbuf  = (float*)(ws + 135680);      // alias xb16 (dead after kvgemm)
    bfx*   hdw   = (bfx*)(ws + 16912896);
    bfx*   Pb    = (bfx*)(ws + 16912896);      // alias hdw (dead after qgemm)
    bfx*   pw16  = (bfx*)(ws + 33690112);
    bfx*   wkvT  = (bfx*)(ws + 33952256);
    bfx*   woT   = (bfx*)(ws + 34476544);
    bfx*   Qr    = (bfx*)(ws + 34738688);
    bfx*   Obuf  = (bfx*)(ws + 34738688);      // alias Qr (dead after dots)
    bfx*   Kr    = (bfx*)(ws + 68293120);
    bfx*   Vt    = (bfx*)(ws + 101847552);

    if (ws_size < 135401984u) return;

    hipLaunchKernelGGL(sincos_kernel,     dim3(64),        dim3(256), 0, stream, tab);
    hipLaunchKernelGGL(mask_stats_kernel, dim3(NB),        dim3(512), 0, stream, mask, m_any, hrows, invnr);
    hipLaunchKernelGGL(cvt_kernel,        dim3(8192),      dim3(256), 0, stream, x, xb16, 2097152);
    hipLaunchKernelGGL(cvt_kernel,        dim3(128),       dim3(256), 0, stream, pw_w, pw16, 32768);
    hipLaunchKernelGGL(tcvt_kernel,       dim3(1024),      dim3(256), 0, stream, w_kv, wkvT, 8, 1024, 262144);
    hipLaunchKernelGGL(tcvt_kernel,       dim3(512),       dim3(256), 0, stream, w_o, woT, 9, 256, 131072);
    hipLaunchKernelGGL(conv_kernel,       dim3(64, 4),     dim3(256), 0, stream, xb16, dw_w, dw_b, hdw);
    hipLaunchKernelGGL(qgemm_kernel,      dim3(4, 256),    dim3(256), 0, stream, hdw, pw16, pw_b, hrows, invnr, tab, Qr);
    hipLaunchKernelGGL(kvgemm_kernel,     dim3(8, 256),    dim3(256), 0, stream, xb16, wkvT, tab, Kr, Vt);
    hipLaunchKernelGGL(dots_kernel,       dim3(4, 4, 16),  dim3(256), 0, stream, Qr, Kr, Sbuf);
    hipLaunchKernelGGL(softmax_kernel,    dim3(SEQ, 16),   dim3(256), 0, stream, m_any, Sbuf, Pb);
    hipLaunchKernelGGL(pv_kernel,         dim3(16, 4, 16), dim3(256), 0, stream, Pb, Vt, Obuf);
    hipLaunchKernelGGL(out_kernel,        dim3(2, 256),    dim3(256), 0, stream, Obuf, woT, b_o, out);
}

// Round 4
// 325.912 us; speedup vs baseline: 3.6388x; 1.1847x over previous
//
#include <hip/hip_runtime.h>
#include <hip/hip_bf16.h>
#include <float.h>
#include <math.h>

typedef __bf16 bfx;
typedef __attribute__((ext_vector_type(8))) __bf16 bf16x8;
typedef __attribute__((ext_vector_type(4))) __bf16 bf16x4;
typedef __attribute__((ext_vector_type(4))) float f32x4;

#define SEQ    512
#define CDIM   256
#define NH     8
#define DH     64
#define INNERD 512
#define RT     32
#define NB     2
#define KW     15
#define PW     7
#define LDT    40   // padded LDS row stride (bf16): 80B rows -> <=2-way conflicts
#define TST    136  // transposed-stage row stride (bf16): 272B, 16B-aligned

// ================= fused prep: cvt x, sincos, cvt pw, tcvt wkv/wo, mask ====
// grid = 8192 (x) + 64 (sincos) + 128 (pw) + 1024 (wkv) + 512 (wo) + 2 (mask)
__global__ void prep_kernel(const float* __restrict__ x,
                            const float* __restrict__ pw_w,
                            const float* __restrict__ w_kv,
                            const float* __restrict__ w_o,
                            const int*   __restrict__ mask,
                            bfx* __restrict__ xb16, bfx* __restrict__ pw16,
                            bfx* __restrict__ wkvT, bfx* __restrict__ woT,
                            float* __restrict__ tab,
                            int* __restrict__ m_any, int* __restrict__ has_rows,
                            float* __restrict__ inv_nr) {
    int bid = blockIdx.x, tid = threadIdx.x;
    if (bid < 8192) {                       // x -> bf16, 4 elems/thread
        int idx = bid * 256 + tid;
        float4 v = ((const float4*)x)[idx];
        bfx* d = xb16 + idx * 4;
        d[0] = (bfx)v.x; d[1] = (bfx)v.y; d[2] = (bfx)v.z; d[3] = (bfx)v.w;
        return;
    }
    int b2 = bid - 8192;
    if (b2 < 64) {                          // sincos table
        int idx = b2 * 256 + tid;
        int i = idx >> 5, j = idx & 31;
        float inv_freq = powf(10000.0f, -(float)j / 32.0f);
        float s, c;
        sincosf((float)i * inv_freq, &s, &c);
        tab[idx * 2] = s; tab[idx * 2 + 1] = c;
        return;
    }
    b2 -= 64;
    if (b2 < 128) {                         // pw_w -> bf16 (already [n][k])
        int idx = b2 * 256 + tid;
        float4 v = ((const float4*)pw_w)[idx];
        bfx* d = pw16 + idx * 4;
        d[0] = (bfx)v.x; d[1] = (bfx)v.y; d[2] = (bfx)v.z; d[3] = (bfx)v.w;
        return;
    }
    b2 -= 128;
    if (b2 < 1024) {                        // w_kv transpose: wkvT[n*256+k]
        int idx = b2 * 256 + tid;
        int k = idx & 255, n = idx >> 8;
        wkvT[idx] = (bfx)w_kv[(size_t)k * 1024 + n];
        return;
    }
    b2 -= 1024;
    if (b2 < 512) {                         // w_o transpose: woT[n*512+k]
        int idx = b2 * 256 + tid;
        int k = idx & 511, n = idx >> 9;
        woT[idx] = (bfx)w_o[(size_t)k * CDIM + n];
        return;
    }
    b2 -= 512;
    {                                       // mask stats, b = b2 (0..1)
        int b = b2;
        #pragma unroll
        for (int half = 0; half < 2; ++half) {
            int i = tid + half * 256;
            int any_col = 0;
            for (int rr = 0; rr < RT; ++rr)
                any_col |= mask[(size_t)(b * RT + rr) * SEQ + i];
            m_any[b * SEQ + i] = any_col ? 1 : 0;
        }
        __shared__ int hr[RT];
        if (tid < RT) {
            int a = 0;
            const int* mrow = mask + (size_t)(b * RT + tid) * SEQ;
            for (int j = 0; j < SEQ; ++j) a |= mrow[j];
            hr[tid] = a ? 1 : 0;
            has_rows[b * RT + tid] = hr[tid];
        }
        __syncthreads();
        if (tid == 0) {
            int s = 0;
            for (int rr = 0; rr < RT; ++rr) s += hr[rr];
            inv_nr[b] = (s > 0) ? rsqrtf((float)s) : 0.0f;
        }
    }
}

// ---------------- depthwise conv1d, register sliding window → hdw bf16 ----
__global__ void conv_kernel(const bfx* __restrict__ xb,
                            const float* __restrict__ dw_w,
                            const float* __restrict__ dw_b,
                            bfx* __restrict__ hdw) {
    int bn = blockIdx.x;
    int i0 = blockIdx.y * 128;
    int c  = threadIdx.x;
    const bfx* xc = xb + (size_t)bn * SEQ * CDIM + c;
    float w[KW];
    #pragma unroll
    for (int k = 0; k < KW; ++k) w[k] = dw_w[c * KW + k];
    float bias = dw_b[c];
    float win[KW];
    #pragma unroll
    for (int k = 0; k < KW; ++k) {
        int p = i0 - PW + k;
        win[k] = (p >= 0 && p < SEQ) ? (float)xc[(size_t)p * CDIM] : 0.0f;
    }
    for (int i = i0; i < i0 + 128; ++i) {
        float acc = bias;
        #pragma unroll
        for (int k = 0; k < KW; ++k) acc += win[k] * w[k];
        hdw[((size_t)bn * SEQ + i) * CDIM + c] = (bfx)acc;
        #pragma unroll
        for (int k = 0; k < KW - 1; ++k) win[k] = win[k + 1];
        int p = i + PW + 1;
        win[KW - 1] = (p < SEQ) ? (float)xc[(size_t)p * CDIM] : 0.0f;
    }
}

// ---------------- shared 128x128 MFMA tile ---------------------------------
// A [m][k] row-major, B [n][k] row-major (B^T), K % 32 == 0.
__device__ __forceinline__ void gemm_tile(const bfx* __restrict__ A, int lda,
                                          const bfx* __restrict__ B, int ldb,
                                          int m0, int n0, int K,
                                          bfx* As, bfx* Bs, f32x4 acc[4][4]) {
    int tid = threadIdx.x;
    int wave = tid >> 6, lane = tid & 63;
    int wm = (wave >> 1) * 64, wn = (wave & 1) * 64;
    int col = lane & 15, quad = lane >> 4;
    for (int k0 = 0; k0 < K; k0 += 32) {
        #pragma unroll
        for (int r = 0; r < 2; ++r) {
            int v = tid + r * 256;
            int row = v >> 2, kv = (v & 3) * 8;
            *(bf16x8*)&As[row * LDT + kv] = *(const bf16x8*)&A[(size_t)(m0 + row) * lda + k0 + kv];
            *(bf16x8*)&Bs[row * LDT + kv] = *(const bf16x8*)&B[(size_t)(n0 + row) * ldb + k0 + kv];
        }
        __syncthreads();
        bf16x8 af[4], bff[4];
        #pragma unroll
        for (int f = 0; f < 4; ++f) {
            af[f]  = *(const bf16x8*)&As[(wm + f * 16 + col) * LDT + quad * 8];
            bff[f] = *(const bf16x8*)&Bs[(wn + f * 16 + col) * LDT + quad * 8];
        }
        #pragma unroll
        for (int mi = 0; mi < 4; ++mi)
            #pragma unroll
            for (int ni = 0; ni < 4; ++ni)
                acc[mi][ni] = __builtin_amdgcn_mfma_f32_16x16x32_bf16(af[mi], bff[ni], acc[mi][ni], 0, 0, 0);
        __syncthreads();
    }
}

#define GEMM_PROLOGUE \
    __shared__ __align__(16) bfx smem[2 * 128 * LDT]; \
    bfx* As = smem; bfx* Bs = smem + 128 * LDT; \
    f32x4 acc[4][4]; \
    _Pragma("unroll") for (int i_ = 0; i_ < 4; ++i_) \
    _Pragma("unroll") for (int j_ = 0; j_ < 4; ++j_) acc[i_][j_] = (f32x4){0.f, 0.f, 0.f, 0.f}; \
    int tid = threadIdx.x; \
    int wave = tid >> 6, lane = tid & 63; \
    int wm = (wave >> 1) * 64, wn = (wave & 1) * 64; \
    int col = lane & 15, quad = lane >> 4;

// ---------------- q GEMM: hdw[32768,256] @ pw16^T -> rotary -> Qr ----------
__global__ void qgemm_kernel(const bfx* __restrict__ A, const bfx* __restrict__ B,
                             const float* __restrict__ pw_b,
                             const int* __restrict__ has_rows,
                             const float* __restrict__ inv_nr,
                             const float* __restrict__ tab,
                             bfx* __restrict__ Qr) {
    GEMM_PROLOGUE
    int m0 = blockIdx.y * 128, n0 = blockIdx.x * 128;
    gemm_tile(A, CDIM, B, CDIM, m0, n0, CDIM, As, Bs, acc);
    int bn = m0 >> 9, b = bn >> 5, rr = bn & 31;
    float zs = has_rows[bn] ? 0.125f * inv_nr[b] : 0.0f;
    #pragma unroll
    for (int mi = 0; mi < 4; ++mi)
        #pragma unroll
        for (int ni = 0; ni < 4; ++ni)
            #pragma unroll
            for (int rg = 0; rg < 4; ++rg) {
                int m = m0 + wm + mi * 16 + quad * 4 + rg;
                int i = m & (SEQ - 1);
                int o = n0 + wn + ni * 16 + col;
                float v  = acc[mi][ni][rg];
                float vp = __shfl_xor(v, 1);
                float q  = v + pw_b[o];
                float qp = vp + pw_b[o ^ 1];
                int h = o >> 6, dd = o & 63, j = dd >> 1;
                float sn = tab[(i * 32 + j) * 2], cs = tab[(i * 32 + j) * 2 + 1];
                float r = (o & 1) ? (q * cs + qp * sn) : (q * cs - qp * sn);
                Qr[((size_t)((b * NH + h) * SEQ + i)) * 2048 + rr * 64 + dd] = (bfx)(r * zs);
            }
}

// ---------------- kv GEMM: xb[32768,256] @ wkvT^T ---------------------------
// blockIdx.x<4: K half -> rotary -> Kr[bh][i][rr*64+dd]
// blockIdx.x>=4: V half -> LDS-transposed -> coalesced Vt[bh][rd][i] stores
__global__ void kvgemm_kernel(const bfx* __restrict__ A, const bfx* __restrict__ B,
                              const float* __restrict__ tab,
                              bfx* __restrict__ Kr, bfx* __restrict__ Vt) {
    GEMM_PROLOGUE
    int m0 = blockIdx.y * 128, n0 = blockIdx.x * 128;
    gemm_tile(A, CDIM, B, CDIM, m0, n0, CDIM, As, Bs, acc);
    int bn = m0 >> 9, b = bn >> 5, rr = bn & 31;
    if (blockIdx.x < 4) {
        // ---- K half: rotary epilogue, direct 32B-segment stores ----
        #pragma unroll
        for (int mi = 0; mi < 4; ++mi)
            #pragma unroll
            for (int ni = 0; ni < 4; ++ni)
                #pragma unroll
                for (int rg = 0; rg < 4; ++rg) {
                    int m = m0 + wm + mi * 16 + quad * 4 + rg;
                    int i = m & (SEQ - 1);
                    int o = n0 + wn + ni * 16 + col;
                    float v  = acc[mi][ni][rg];
                    float vp = __shfl_xor(v, 1);
                    int h = o >> 6, dd = o & 63, j = dd >> 1;
                    float sn = tab[(i * 32 + j) * 2], cs = tab[(i * 32 + j) * 2 + 1];
                    float r = (o & 1) ? (v * cs + vp * sn) : (v * cs - vp * sn);
                    Kr[((size_t)((b * NH + h) * SEQ + i)) * 2048 + rr * 64 + dd] = (bfx)r;
                }
    } else {
        // ---- V half: two 64-row LDS transpose passes -> coalesced Vt ----
        int no0 = n0 - INNERD;          // 0,128,256,384
        int h0  = no0 >> 6;             // head base (0,2,4,6)
        int i0  = m0 & (SEQ - 1);
        bfx* Ts = smem;                 // 64 x TST bf16 = 17408 B <= 20480 B
        #pragma unroll
        for (int p = 0; p < 2; ++p) {
            __syncthreads();
            if ((wave & 1) == p) {      // waves with wn == p*64 own these cols
                #pragma unroll
                for (int mi = 0; mi < 4; ++mi)
                    #pragma unroll
                    for (int ni = 0; ni < 4; ++ni) {
                        int nl = ni * 16 + col;          // 0..63
                        int ml = wm + mi * 16 + quad * 4;
                        bf16x4 pk;
                        #pragma unroll
                        for (int rg = 0; rg < 4; ++rg) pk[rg] = (bfx)acc[mi][ni][rg];
                        *(bf16x4*)&Ts[nl * TST + ml] = pk;
                    }
            }
            __syncthreads();
            #pragma unroll
            for (int e = 0; e < 4; ++e) {
                int row = (tid >> 4) + e * 16;           // 0..63 = dd
                int chunk = tid & 15;
                bf16x8 v = *(const bf16x8*)&Ts[row * TST + chunk * 8];
                size_t rv = (size_t)(b * NH + h0 + p) * 2048 + rr * 64 + row;
                *(bf16x8*)&Vt[rv * SEQ + i0 + chunk * 8] = v;
            }
        }
    }
}

// ---------------- dots: per bh: S = Qr[512,2048] @ Kr^T --------------------
// XCD-swizzled: all 16 tiles of one bh share a dispatch-id residue (L2 reuse)
__global__ void dots_kernel(const bfx* __restrict__ Qr, const bfx* __restrict__ Kr,
                            float* __restrict__ Sbuf) {
    GEMM_PROLOGUE
    int flat = blockIdx.x + gridDim.x * (blockIdx.y + gridDim.y * blockIdx.z); // 0..255
    int bh   = (flat & 7) | (((flat >> 7) & 1) << 3);
    int tile = (flat >> 3) & 15;
    int m0 = (tile >> 2) * 128, n0 = (tile & 3) * 128;
    const bfx* A = Qr + (size_t)bh * SEQ * 2048;
    const bfx* B = Kr + (size_t)bh * SEQ * 2048;
    gemm_tile(A, 2048, B, 2048, m0, n0, 2048, As, Bs, acc);
    float* S = Sbuf + (size_t)bh * SEQ * SEQ;
    #pragma unroll
    for (int mi = 0; mi < 4; ++mi)
        #pragma unroll
        for (int ni = 0; ni < 4; ++ni)
            #pragma unroll
            for (int rg = 0; rg < 4; ++rg) {
                int i = m0 + wm + mi * 16 + quad * 4 + rg;
                int j = n0 + wn + ni * 16 + col;
                S[(size_t)i * SEQ + j] = acc[mi][ni][rg];
            }
}

// ---------------- softmax: Sbuf f32 -> Pb bf16 -----------------------------
__global__ void softmax_kernel(const int* __restrict__ m_any,
                               const float* __restrict__ Sbuf,
                               bfx* __restrict__ Pb) {
    int i = blockIdx.x, bh = blockIdx.y;
    int b = bh >> 3;
    const float* row = Sbuf + ((size_t)bh * SEQ + i) * SEQ;
    bfx* prow = Pb + ((size_t)bh * SEQ + i) * SEQ;
    const int* ma = m_any + b * SEQ;
    int fi = ma[i];
    int t = threadIdx.x;
    float v0 = (fi && ma[t])       ? row[t]       : -FLT_MAX;
    float v1 = (fi && ma[t + 256]) ? row[t + 256] : -FLT_MAX;
    __shared__ float red[256];
    red[t] = fmaxf(v0, v1);
    __syncthreads();
    for (int s = 128; s > 0; s >>= 1) {
        if (t < s) red[t] = fmaxf(red[t], red[t + s]);
        __syncthreads();
    }
    float mx = red[0];
    __syncthreads();
    float e0 = __expf(v0 - mx);
    float e1 = __expf(v1 - mx);
    red[t] = e0 + e1;
    __syncthreads();
    for (int s = 128; s > 0; s >>= 1) {
        if (t < s) red[t] += red[t + s];
        __syncthreads();
    }
    float inv = 1.0f / red[0];
    prow[t]       = (bfx)(e0 * inv);
    prow[t + 256] = (bfx)(e1 * inv);
}

// ---------------- PV: per bh: O[i,rd] = Pb[512,512] @ Vt[2048,512]^T -------
__global__ void pv_kernel(const bfx* __restrict__ Pb, const bfx* __restrict__ Vt,
                          bfx* __restrict__ Obuf) {
    GEMM_PROLOGUE
    int bh = blockIdx.z;
    int b = bh >> 3, h = bh & 7;
    int m0 = blockIdx.y * 128, n0 = blockIdx.x * 128;
    const bfx* A = Pb + (size_t)bh * SEQ * SEQ;
    const bfx* B = Vt + (size_t)bh * 2048 * SEQ;
    gemm_tile(A, SEQ, B, SEQ, m0, n0, SEQ, As, Bs, acc);
    #pragma unroll
    for (int mi = 0; mi < 4; ++mi)
        #pragma unroll
        for (int ni = 0; ni < 4; ++ni)
            #pragma unroll
            for (int rg = 0; rg < 4; ++rg) {
                int i = m0 + wm + mi * 16 + quad * 4 + rg;
                int rd = n0 + wn + ni * 16 + col;
                int rr = rd >> 6, dd = rd & 63;
                Obuf[((size_t)((b * RT + rr) * SEQ + i)) * INNERD + h * DH + dd] =
                    (bfx)acc[mi][ni][rg];
            }
}

// ---------------- out: Obuf[32768,512] @ woT^T + b_o -> f32 ----------------
__global__ void out_kernel(const bfx* __restrict__ A, const bfx* __restrict__ B,
                           const float* __restrict__ b_o, float* __restrict__ out) {
    GEMM_PROLOGUE
    int m0 = blockIdx.y * 128, n0 = blockIdx.x * 128;
    gemm_tile(A, INNERD, B, INNERD, m0, n0, INNERD, As, Bs, acc);
    #pragma unroll
    for (int mi = 0; mi < 4; ++mi)
        #pragma unroll
        for (int ni = 0; ni < 4; ++ni)
            #pragma unroll
            for (int rg = 0; rg < 4; ++rg) {
                int m = m0 + wm + mi * 16 + quad * 4 + rg;
                int c = n0 + wn + ni * 16 + col;
                out[(size_t)m * CDIM + c] = acc[mi][ni][rg] + b_o[c];
            }
}

// ---------------- workspace layout (bytes) — unchanged from R3 -------------
// 0         tab f32                                 131072
// 131072    m_any int32[1024]                         4096
// 135168    has_rows int32[64]                         256
// 135424    inv_nr f32 (+pad)                          256
// 135680    xb16 bf16 [8388608]   16777216   (REUSED: Sbuf f32 after kvgemm)
// 16912896  hdw  bf16 [8388608]   16777216   (REUSED: Pb bf16 after qgemm)
// 33690112  pw16 bf16                          262144
// 33952256  wkvT bf16                          524288
// 34476544  woT  bf16                          262144
// 34738688  Qr   bf16 [16777216]  33554432   (REUSED: Obuf after dots)
// 68293120  Kr   bf16 [16777216]  33554432
// 101847552 Vt   bf16 [16777216]  33554432
// end 135401984

extern "C" void kernel_launch(void* const* d_in, const int* in_sizes, int n_in,
                              void* d_out, int out_size, void* d_ws, size_t ws_size,
                              hipStream_t stream) {
    const float* x    = (const float*)d_in[0];
    const int*   mask = (const int*)d_in[1];
    const float* dw_w = (const float*)d_in[3];
    const float* dw_b = (const float*)d_in[4];
    const float* pw_w = (const float*)d_in[5];
    const float* pw_b = (const float*)d_in[6];
    const float* w_kv = (const float*)d_in[7];
    const float* w_o  = (const float*)d_in[8];
    const float* b_o  = (const float*)d_in[9];
    float* out = (float*)d_out;

    char* ws = (char*)d_ws;
    float* tab   = (float*)(ws + 0);
    int*   m_any = (int*)(ws + 131072);
    int*   hrows = (int*)(ws + 135168);
    float* invnr = (float*)(ws + 135424);
    bfx*   xb16  = (bfx*)(ws + 135680);
    float* Sbuf  = (float*)(ws + 135680);      // alias xb16 (dead after kvgemm)
    bfx*   hdw   = (bfx*)(ws + 16912896);
    bfx*   Pb    = (bfx*)(ws + 16912896);      // alias hdw (dead after qgemm)
    bfx*   pw16  = (bfx*)(ws + 33690112);
    bfx*   wkvT  = (bfx*)(ws + 33952256);
    bfx*   woT   = (bfx*)(ws + 34476544);
    bfx*   Qr    = (bfx*)(ws + 34738688);
    bfx*   Obuf  = (bfx*)(ws + 34738688);      // alias Qr (dead after dots)
    bfx*   Kr    = (bfx*)(ws + 68293120);
    bfx*   Vt    = (bfx*)(ws + 101847552);

    if (ws_size < 135401984u) return;

    hipLaunchKernelGGL(prep_kernel,  dim3(9922),      dim3(256), 0, stream,
                       x, pw_w, w_kv, w_o, mask, xb16, pw16, wkvT, woT,
                       tab, m_any, hrows, invnr);
    hipLaunchKernelGGL(conv_kernel,  dim3(64, 4),     dim3(256), 0, stream, xb16, dw_w, dw_b, hdw);
    hipLaunchKernelGGL(qgemm_kernel, dim3(4, 256),    dim3(256), 0, stream, hdw, pw16, pw_b, hrows, invnr, tab, Qr);
    hipLaunchKernelGGL(kvgemm_kernel,dim3(8, 256),    dim3(256), 0, stream, xb16, wkvT, tab, Kr, Vt);
    hipLaunchKernelGGL(dots_kernel,  dim3(4, 4, 16),  dim3(256), 0, stream, Qr, Kr, Sbuf);
    hipLaunchKernelGGL(softmax_kernel, dim3(SEQ, 16), dim3(256), 0, stream, m_any, Sbuf, Pb);
    hipLaunchKernelGGL(pv_kernel,    dim3(16, 4, 16), dim3(256), 0, stream, Pb, Vt, Obuf);
    hipLaunchKernelGGL(out_kernel,   dim3(2, 256),    dim3(256), 0, stream, Obuf, woT, b_o, out);
}

// Round 5
// 301.154 us; speedup vs baseline: 3.9380x; 1.0822x over previous
//
#include <hip/hip_runtime.h>
#include <hip/hip_bf16.h>
#include <float.h>
#include <math.h>

typedef __bf16 bfx;
typedef __attribute__((ext_vector_type(8))) __bf16 bf16x8;
typedef __attribute__((ext_vector_type(4))) __bf16 bf16x4;
typedef __attribute__((ext_vector_type(2))) __bf16 bf16x2;
typedef __attribute__((ext_vector_type(4))) float f32x4;

#define SEQ    512
#define CDIM   256
#define NH     8
#define DH     64
#define INNERD 512
#define RT     32
#define NB     2
#define KW     15
#define PW     7
#define LDT    40   // padded LDS row stride (bf16): 80B rows -> <=2-way conflicts
#define TST    136  // transposed-stage row stride (bf16): 272B, 16B-aligned

// ================= fused prep: cvt x, sincos, cvt pw, tcvt wkv/wo, mask ====
// grid = 8192 (x) + 64 (sincos) + 128 (pw) + 1024 (wkv) + 512 (wo) + 2 (mask)
__global__ void prep_kernel(const float* __restrict__ x,
                            const float* __restrict__ pw_w,
                            const float* __restrict__ w_kv,
                            const float* __restrict__ w_o,
                            const int*   __restrict__ mask,
                            bfx* __restrict__ xb16, bfx* __restrict__ pw16,
                            bfx* __restrict__ wkvT, bfx* __restrict__ woT,
                            float* __restrict__ tab,
                            int* __restrict__ m_any, int* __restrict__ has_rows,
                            float* __restrict__ inv_nr) {
    int bid = blockIdx.x, tid = threadIdx.x;
    if (bid < 8192) {                       // x -> bf16, 4 elems/thread
        int idx = bid * 256 + tid;
        float4 v = ((const float4*)x)[idx];
        bfx* d = xb16 + idx * 4;
        d[0] = (bfx)v.x; d[1] = (bfx)v.y; d[2] = (bfx)v.z; d[3] = (bfx)v.w;
        return;
    }
    int b2 = bid - 8192;
    if (b2 < 64) {                          // sincos table
        int idx = b2 * 256 + tid;
        int i = idx >> 5, j = idx & 31;
        float inv_freq = powf(10000.0f, -(float)j / 32.0f);
        float s, c;
        sincosf((float)i * inv_freq, &s, &c);
        tab[idx * 2] = s; tab[idx * 2 + 1] = c;
        return;
    }
    b2 -= 64;
    if (b2 < 128) {                         // pw_w -> bf16 (already [n][k])
        int idx = b2 * 256 + tid;
        float4 v = ((const float4*)pw_w)[idx];
        bfx* d = pw16 + idx * 4;
        d[0] = (bfx)v.x; d[1] = (bfx)v.y; d[2] = (bfx)v.z; d[3] = (bfx)v.w;
        return;
    }
    b2 -= 128;
    if (b2 < 1024) {                        // w_kv transpose: wkvT[n*256+k]
        int idx = b2 * 256 + tid;
        int k = idx & 255, n = idx >> 8;
        wkvT[idx] = (bfx)w_kv[(size_t)k * 1024 + n];
        return;
    }
    b2 -= 1024;
    if (b2 < 512) {                         // w_o transpose: woT[n*512+k]
        int idx = b2 * 256 + tid;
        int k = idx & 511, n = idx >> 9;
        woT[idx] = (bfx)w_o[(size_t)k * CDIM + n];
        return;
    }
    b2 -= 512;
    {                                       // mask stats, b = b2 (0..1)
        int b = b2;
        #pragma unroll
        for (int half = 0; half < 2; ++half) {
            int i = tid + half * 256;
            int any_col = 0;
            for (int rr = 0; rr < RT; ++rr)
                any_col |= mask[(size_t)(b * RT + rr) * SEQ + i];
            m_any[b * SEQ + i] = any_col ? 1 : 0;
        }
        __shared__ int hr[RT];
        if (tid < RT) {
            int a = 0;
            const int* mrow = mask + (size_t)(b * RT + tid) * SEQ;
            for (int j = 0; j < SEQ; ++j) a |= mrow[j];
            hr[tid] = a ? 1 : 0;
            has_rows[b * RT + tid] = hr[tid];
        }
        __syncthreads();
        if (tid == 0) {
            int s = 0;
            for (int rr = 0; rr < RT; ++rr) s += hr[rr];
            inv_nr[b] = (s > 0) ? rsqrtf((float)s) : 0.0f;
        }
    }
}

// ---------------- depthwise conv1d: 2 ch/thread, 32-row chunks -------------
// grid (64, 8), block 256 = two 128-thread groups, each owns 32 rows.
__global__ void conv_kernel(const bfx* __restrict__ xb,
                            const float* __restrict__ dw_w,
                            const float* __restrict__ dw_b,
                            bfx* __restrict__ hdw) {
    int bn  = blockIdx.x;
    int grp = threadIdx.x >> 7;            // 0..1
    int t   = threadIdx.x & 127;           // 128 threads cover 256 channels
    int i0  = blockIdx.y * 64 + grp * 32;  // 32-row chunk
    int c   = t * 2;
    const bf16x2* xc = (const bf16x2*)(xb + (size_t)bn * SEQ * CDIM) + t;  // stride 128/row
    float w0[KW], w1[KW];
    #pragma unroll
    for (int k = 0; k < KW; ++k) { w0[k] = dw_w[c * KW + k]; w1[k] = dw_w[(c + 1) * KW + k]; }
    float b0 = dw_b[c], b1 = dw_b[c + 1];
    float win0[KW], win1[KW];
    #pragma unroll
    for (int k = 0; k < KW; ++k) {
        int p = i0 - PW + k;
        if (p >= 0 && p < SEQ) {
            bf16x2 v = xc[(size_t)p * 128];
            win0[k] = (float)v[0]; win1[k] = (float)v[1];
        } else { win0[k] = 0.0f; win1[k] = 0.0f; }
    }
    bf16x2* orow = (bf16x2*)(hdw + ((size_t)bn * SEQ + i0) * CDIM) + t;
    for (int i = i0; i < i0 + 32; ++i) {
        float a0 = b0, a1 = b1;
        #pragma unroll
        for (int k = 0; k < KW; ++k) { a0 += win0[k] * w0[k]; a1 += win1[k] * w1[k]; }
        bf16x2 o; o[0] = (bfx)a0; o[1] = (bfx)a1;
        *orow = o;
        orow += 128;
        #pragma unroll
        for (int k = 0; k < KW - 1; ++k) { win0[k] = win0[k + 1]; win1[k] = win1[k + 1]; }
        int p = i + PW + 1;
        if (p < SEQ) {
            bf16x2 v = xc[(size_t)p * 128];
            win0[KW - 1] = (float)v[0]; win1[KW - 1] = (float)v[1];
        } else { win0[KW - 1] = 0.0f; win1[KW - 1] = 0.0f; }
    }
}

// ---------------- shared 128x128 MFMA tile ---------------------------------
// A [m][k] row-major, B [n][k] row-major (B^T), K % 32 == 0.
__device__ __forceinline__ void gemm_tile(const bfx* __restrict__ A, int lda,
                                          const bfx* __restrict__ B, int ldb,
                                          int m0, int n0, int K,
                                          bfx* As, bfx* Bs, f32x4 acc[4][4]) {
    int tid = threadIdx.x;
    int wave = tid >> 6, lane = tid & 63;
    int wm = (wave >> 1) * 64, wn = (wave & 1) * 64;
    int col = lane & 15, quad = lane >> 4;
    for (int k0 = 0; k0 < K; k0 += 32) {
        #pragma unroll
        for (int r = 0; r < 2; ++r) {
            int v = tid + r * 256;
            int row = v >> 2, kv = (v & 3) * 8;
            *(bf16x8*)&As[row * LDT + kv] = *(const bf16x8*)&A[(size_t)(m0 + row) * lda + k0 + kv];
            *(bf16x8*)&Bs[row * LDT + kv] = *(const bf16x8*)&B[(size_t)(n0 + row) * ldb + k0 + kv];
        }
        __syncthreads();
        bf16x8 af[4], bff[4];
        #pragma unroll
        for (int f = 0; f < 4; ++f) {
            af[f]  = *(const bf16x8*)&As[(wm + f * 16 + col) * LDT + quad * 8];
            bff[f] = *(const bf16x8*)&Bs[(wn + f * 16 + col) * LDT + quad * 8];
        }
        #pragma unroll
        for (int mi = 0; mi < 4; ++mi)
            #pragma unroll
            for (int ni = 0; ni < 4; ++ni)
                acc[mi][ni] = __builtin_amdgcn_mfma_f32_16x16x32_bf16(af[mi], bff[ni], acc[mi][ni], 0, 0, 0);
        __syncthreads();
    }
}

#define GEMM_PROLOGUE \
    __shared__ __align__(16) bfx smem[2 * 128 * LDT]; \
    bfx* As = smem; bfx* Bs = smem + 128 * LDT; \
    f32x4 acc[4][4]; \
    _Pragma("unroll") for (int i_ = 0; i_ < 4; ++i_) \
    _Pragma("unroll") for (int j_ = 0; j_ < 4; ++j_) acc[i_][j_] = (f32x4){0.f, 0.f, 0.f, 0.f}; \
    int tid = threadIdx.x; \
    int wave = tid >> 6, lane = tid & 63; \
    int wm = (wave >> 1) * 64, wn = (wave & 1) * 64; \
    int col = lane & 15, quad = lane >> 4;

// ---------------- q GEMM: hdw[32768,256] @ pw16^T -> rotary -> Qr ----------
__global__ void qgemm_kernel(const bfx* __restrict__ A, const bfx* __restrict__ B,
                             const float* __restrict__ pw_b,
                             const int* __restrict__ has_rows,
                             const float* __restrict__ inv_nr,
                             const float* __restrict__ tab,
                             bfx* __restrict__ Qr) {
    GEMM_PROLOGUE
    int m0 = blockIdx.y * 128, n0 = blockIdx.x * 128;
    gemm_tile(A, CDIM, B, CDIM, m0, n0, CDIM, As, Bs, acc);
    int bn = m0 >> 9, b = bn >> 5, rr = bn & 31;
    float zs = has_rows[bn] ? 0.125f * inv_nr[b] : 0.0f;
    #pragma unroll
    for (int mi = 0; mi < 4; ++mi)
        #pragma unroll
        for (int ni = 0; ni < 4; ++ni)
            #pragma unroll
            for (int rg = 0; rg < 4; ++rg) {
                int m = m0 + wm + mi * 16 + quad * 4 + rg;
                int i = m & (SEQ - 1);
                int o = n0 + wn + ni * 16 + col;
                float v  = acc[mi][ni][rg];
                float vp = __shfl_xor(v, 1);
                float q  = v + pw_b[o];
                float qp = vp + pw_b[o ^ 1];
                int h = o >> 6, dd = o & 63, j = dd >> 1;
                float sn = tab[(i * 32 + j) * 2], cs = tab[(i * 32 + j) * 2 + 1];
                float r = (o & 1) ? (q * cs + qp * sn) : (q * cs - qp * sn);
                Qr[((size_t)((b * NH + h) * SEQ + i)) * 2048 + rr * 64 + dd] = (bfx)(r * zs);
            }
}

// ---------------- kv GEMM: xb[32768,256] @ wkvT^T ---------------------------
// blockIdx.x<4: K half -> rotary -> Kr[bh][i][rr*64+dd]
// blockIdx.x>=4: V half -> LDS-transposed -> coalesced Vt[bh][rd][i] stores
__global__ void kvgemm_kernel(const bfx* __restrict__ A, const bfx* __restrict__ B,
                              const float* __restrict__ tab,
                              bfx* __restrict__ Kr, bfx* __restrict__ Vt) {
    GEMM_PROLOGUE
    int m0 = blockIdx.y * 128, n0 = blockIdx.x * 128;
    gemm_tile(A, CDIM, B, CDIM, m0, n0, CDIM, As, Bs, acc);
    int bn = m0 >> 9, b = bn >> 5, rr = bn & 31;
    if (blockIdx.x < 4) {
        // ---- K half: rotary epilogue, direct 32B-segment stores ----
        #pragma unroll
        for (int mi = 0; mi < 4; ++mi)
            #pragma unroll
            for (int ni = 0; ni < 4; ++ni)
                #pragma unroll
                for (int rg = 0; rg < 4; ++rg) {
                    int m = m0 + wm + mi * 16 + quad * 4 + rg;
                    int i = m & (SEQ - 1);
                    int o = n0 + wn + ni * 16 + col;
                    float v  = acc[mi][ni][rg];
                    float vp = __shfl_xor(v, 1);
                    int h = o >> 6, dd = o & 63, j = dd >> 1;
                    float sn = tab[(i * 32 + j) * 2], cs = tab[(i * 32 + j) * 2 + 1];
                    float r = (o & 1) ? (v * cs + vp * sn) : (v * cs - vp * sn);
                    Kr[((size_t)((b * NH + h) * SEQ + i)) * 2048 + rr * 64 + dd] = (bfx)r;
                }
    } else {
        // ---- V half: two 64-row LDS transpose passes -> coalesced Vt ----
        int no0 = n0 - INNERD;          // 0,128,256,384
        int h0  = no0 >> 6;             // head base (0,2,4,6)
        int i0  = m0 & (SEQ - 1);
        bfx* Ts = smem;                 // 64 x TST bf16 = 17408 B <= 20480 B
        #pragma unroll
        for (int p = 0; p < 2; ++p) {
            __syncthreads();
            if ((wave & 1) == p) {      // waves with wn == p*64 own these cols
                #pragma unroll
                for (int mi = 0; mi < 4; ++mi)
                    #pragma unroll
                    for (int ni = 0; ni < 4; ++ni) {
                        int nl = ni * 16 + col;          // 0..63
                        int ml = wm + mi * 16 + quad * 4;
                        bf16x4 pk;
                        #pragma unroll
                        for (int rg = 0; rg < 4; ++rg) pk[rg] = (bfx)acc[mi][ni][rg];
                        *(bf16x4*)&Ts[nl * TST + ml] = pk;
                    }
            }
            __syncthreads();
            #pragma unroll
            for (int e = 0; e < 4; ++e) {
                int row = (tid >> 4) + e * 16;           // 0..63 = dd
                int chunk = tid & 15;
                bf16x8 v = *(const bf16x8*)&Ts[row * TST + chunk * 8];
                size_t rv = (size_t)(b * NH + h0 + p) * 2048 + rr * 64 + row;
                *(bf16x8*)&Vt[rv * SEQ + i0 + chunk * 8] = v;
            }
        }
    }
}

// ---------------- dots: per bh: S = Qr[512,2048] @ Kr^T --------------------
// XCD-swizzled: all 16 tiles of one bh share a dispatch-id residue (L2 reuse)
__global__ void dots_kernel(const bfx* __restrict__ Qr, const bfx* __restrict__ Kr,
                            float* __restrict__ Sbuf) {
    GEMM_PROLOGUE
    int flat = blockIdx.x + gridDim.x * (blockIdx.y + gridDim.y * blockIdx.z); // 0..255
    int bh   = (flat & 7) | (((flat >> 7) & 1) << 3);
    int tile = (flat >> 3) & 15;
    int m0 = (tile >> 2) * 128, n0 = (tile & 3) * 128;
    const bfx* A = Qr + (size_t)bh * SEQ * 2048;
    const bfx* B = Kr + (size_t)bh * SEQ * 2048;
    gemm_tile(A, 2048, B, 2048, m0, n0, 2048, As, Bs, acc);
    float* S = Sbuf + (size_t)bh * SEQ * SEQ;
    #pragma unroll
    for (int mi = 0; mi < 4; ++mi)
        #pragma unroll
        for (int ni = 0; ni < 4; ++ni)
            #pragma unroll
            for (int rg = 0; rg < 4; ++rg) {
                int i = m0 + wm + mi * 16 + quad * 4 + rg;
                int j = n0 + wn + ni * 16 + col;
                S[(size_t)i * SEQ + j] = acc[mi][ni][rg];
            }
}

// ---------------- softmax: Sbuf f32 -> Pb bf16 -----------------------------
__global__ void softmax_kernel(const int* __restrict__ m_any,
                               const float* __restrict__ Sbuf,
                               bfx* __restrict__ Pb) {
    int i = blockIdx.x, bh = blockIdx.y;
    int b = bh >> 3;
    const float* row = Sbuf + ((size_t)bh * SEQ + i) * SEQ;
    bfx* prow = Pb + ((size_t)bh * SEQ + i) * SEQ;
    const int* ma = m_any + b * SEQ;
    int fi = ma[i];
    int t = threadIdx.x;
    float v0 = (fi && ma[t])       ? row[t]       : -FLT_MAX;
    float v1 = (fi && ma[t + 256]) ? row[t + 256] : -FLT_MAX;
    __shared__ float red[256];
    red[t] = fmaxf(v0, v1);
    __syncthreads();
    for (int s = 128; s > 0; s >>= 1) {
        if (t < s) red[t] = fmaxf(red[t], red[t + s]);
        __syncthreads();
    }
    float mx = red[0];
    __syncthreads();
    float e0 = __expf(v0 - mx);
    float e1 = __expf(v1 - mx);
    red[t] = e0 + e1;
    __syncthreads();
    for (int s = 128; s > 0; s >>= 1) {
        if (t < s) red[t] += red[t + s];
        __syncthreads();
    }
    float inv = 1.0f / red[0];
    prow[t]       = (bfx)(e0 * inv);
    prow[t + 256] = (bfx)(e1 * inv);
}

// ---------------- PV: per bh: O[i,rd] = Pb[512,512] @ Vt[2048,512]^T -------
__global__ void pv_kernel(const bfx* __restrict__ Pb, const bfx* __restrict__ Vt,
                          bfx* __restrict__ Obuf) {
    GEMM_PROLOGUE
    int bh = blockIdx.z;
    int b = bh >> 3, h = bh & 7;
    int m0 = blockIdx.y * 128, n0 = blockIdx.x * 128;
    const bfx* A = Pb + (size_t)bh * SEQ * SEQ;
    const bfx* B = Vt + (size_t)bh * 2048 * SEQ;
    gemm_tile(A, SEQ, B, SEQ, m0, n0, SEQ, As, Bs, acc);
    #pragma unroll
    for (int mi = 0; mi < 4; ++mi)
        #pragma unroll
        for (int ni = 0; ni < 4; ++ni)
            #pragma unroll
            for (int rg = 0; rg < 4; ++rg) {
                int i = m0 + wm + mi * 16 + quad * 4 + rg;
                int rd = n0 + wn + ni * 16 + col;
                int rr = rd >> 6, dd = rd & 63;
                Obuf[((size_t)((b * RT + rr) * SEQ + i)) * INNERD + h * DH + dd] =
                    (bfx)acc[mi][ni][rg];
            }
}

// ---------------- out: Obuf[32768,512] @ woT^T + b_o -> f32 ----------------
__global__ void out_kernel(const bfx* __restrict__ A, const bfx* __restrict__ B,
                           const float* __restrict__ b_o, float* __restrict__ out) {
    GEMM_PROLOGUE
    int m0 = blockIdx.y * 128, n0 = blockIdx.x * 128;
    gemm_tile(A, INNERD, B, INNERD, m0, n0, INNERD, As, Bs, acc);
    #pragma unroll
    for (int mi = 0; mi < 4; ++mi)
        #pragma unroll
        for (int ni = 0; ni < 4; ++ni)
            #pragma unroll
            for (int rg = 0; rg < 4; ++rg) {
                int m = m0 + wm + mi * 16 + quad * 4 + rg;
                int c = n0 + wn + ni * 16 + col;
                out[(size_t)m * CDIM + c] = acc[mi][ni][rg] + b_o[c];
            }
}

// ---------------- workspace layout (bytes) — unchanged -------------
// 0         tab f32                                 131072
// 131072    m_any int32[1024]                         4096
// 135168    has_rows int32[64]                         256
// 135424    inv_nr f32 (+pad)                          256
// 135680    xb16 bf16 [8388608]   16777216   (REUSED: Sbuf f32 after kvgemm)
// 16912896  hdw  bf16 [8388608]   16777216   (REUSED: Pb bf16 after qgemm)
// 33690112  pw16 bf16                          262144
// 33952256  wkvT bf16                          524288
// 34476544  woT  bf16                          262144
// 34738688  Qr   bf16 [16777216]  33554432   (REUSED: Obuf after dots)
// 68293120  Kr   bf16 [16777216]  33554432
// 101847552 Vt   bf16 [16777216]  33554432
// end 135401984

extern "C" void kernel_launch(void* const* d_in, const int* in_sizes, int n_in,
                              void* d_out, int out_size, void* d_ws, size_t ws_size,
                              hipStream_t stream) {
    const float* x    = (const float*)d_in[0];
    const int*   mask = (const int*)d_in[1];
    const float* dw_w = (const float*)d_in[3];
    const float* dw_b = (const float*)d_in[4];
    const float* pw_w = (const float*)d_in[5];
    const float* pw_b = (const float*)d_in[6];
    const float* w_kv = (const float*)d_in[7];
    const float* w_o  = (const float*)d_in[8];
    const float* b_o  = (const float*)d_in[9];
    float* out = (float*)d_out;

    char* ws = (char*)d_ws;
    float* tab   = (float*)(ws + 0);
    int*   m_any = (int*)(ws + 131072);
    int*   hrows = (int*)(ws + 135168);
    float* invnr = (float*)(ws + 135424);
    bfx*   xb16  = (bfx*)(ws + 135680);
    float* Sbuf  = (float*)(ws + 135680);      // alias xb16 (dead after kvgemm)
    bfx*   hdw   = (bfx*)(ws + 16912896);
    bfx*   Pb    = (bfx*)(ws + 16912896);      // alias hdw (dead after qgemm)
    bfx*   pw16  = (bfx*)(ws + 33690112);
    bfx*   wkvT  = (bfx*)(ws + 33952256);
    bfx*   woT   = (bfx*)(ws + 34476544);
    bfx*   Qr    = (bfx*)(ws + 34738688);
    bfx*   Obuf  = (bfx*)(ws + 34738688);      // alias Qr (dead after dots)
    bfx*   Kr    = (bfx*)(ws + 68293120);
    bfx*   Vt    = (bfx*)(ws + 101847552);

    if (ws_size < 135401984u) return;

    hipLaunchKernelGGL(prep_kernel,  dim3(9922),      dim3(256), 0, stream,
                       x, pw_w, w_kv, w_o, mask, xb16, pw16, wkvT, woT,
                       tab, m_any, hrows, invnr);
    hipLaunchKernelGGL(conv_kernel,  dim3(64, 8),     dim3(256), 0, stream, xb16, dw_w, dw_b, hdw);
    hipLaunchKernelGGL(qgemm_kernel, dim3(4, 256),    dim3(256), 0, stream, hdw, pw16, pw_b, hrows, invnr, tab, Qr);
    hipLaunchKernelGGL(kvgemm_kernel,dim3(8, 256),    dim3(256), 0, stream, xb16, wkvT, tab, Kr, Vt);
    hipLaunchKernelGGL(dots_kernel,  dim3(4, 4, 16),  dim3(256), 0, stream, Qr, Kr, Sbuf);
    hipLaunchKernelGGL(softmax_kernel, dim3(SEQ, 16), dim3(256), 0, stream, m_any, Sbuf, Pb);
    hipLaunchKernelGGL(pv_kernel,    dim3(16, 4, 16), dim3(256), 0, stream, Pb, Vt, Obuf);
    hipLaunchKernelGGL(out_kernel,   dim3(2, 256),    dim3(256), 0, stream, Obuf, woT, b_o, out);
}